// Round 5
// baseline (309.998 us; speedup 1.0000x reference)
//
#include <hip/hip_runtime.h>
#include <math.h>

namespace {

constexpr int B_ = 8, C_ = 256, H_ = 128, W_ = 192;
constexpr int HW = H_ * W_;
constexpr int ND = 9;                  // 2R+1
constexpr int TH = 8;                  // h rows per block
constexpr int TW = 32;                 // w cols per block
constexpr int WPT = 8;                 // w per lane
constexpr int NTHREADS = 320;          // 5 waves; dy = tid>>5 (wave4 upper half stage-only)
constexpr int KC = 4;                  // channels per chunk (2 f16 channel-pairs)
constexpr int NCHUNK = C_ / KC;        // 64
constexpr int F2R = 16;                // staged f2 rows (h0-4 .. h0+11)
constexpr int F2S = 44;                // u32 row stride: 11 (odd) 16B slots -> bank-uniform
constexpr int QPR = 10;                // staged quads per row (40 u32 = w0-4 .. w0+35)

typedef _Float16 h2 __attribute__((ext_vector_type(2)));

__device__ __forceinline__ unsigned pk2(float x, float y) {
#if __has_builtin(__builtin_amdgcn_cvt_pkrtz)
    return __builtin_bit_cast(unsigned, __builtin_amdgcn_cvt_pkrtz(x, y));
#else
    h2 t; t.x = (_Float16)x; t.y = (_Float16)y;
    return __builtin_bit_cast(unsigned, t);
#endif
}

__device__ __forceinline__ float dot2f(unsigned a, unsigned b, float c) {
#if __has_builtin(__builtin_amdgcn_fdot2)
    return __builtin_amdgcn_fdot2(__builtin_bit_cast(h2, a),
                                  __builtin_bit_cast(h2, b), c, false);
#else
    const h2 ha = __builtin_bit_cast(h2, a), hb = __builtin_bit_cast(h2, b);
    return fmaf((float)ha.x, (float)hb.x, fmaf((float)ha.y, (float)hb.y, c));
#endif
}

__global__ __launch_bounds__(NTHREADS)
void local_corr_kernel(const float* __restrict__ f1g,
                       const float* __restrict__ f2g,
                       float* __restrict__ outg)
{
    __shared__ unsigned sf2[2][2][F2R][F2S];   // 11.3 KB: [buf][cpair][row][col]

    // XCD swizzle: batch image b == XCD id (96 blocks = one full image per XCD)
    const int m  = blockIdx.x;             // 0..767
    const int k  = m >> 3;                 // 0..95
    const int b  = m & 7;
    const int bx = k % 6;
    const int by = k / 6;                  // 0..15
    const int w0 = bx * TW;
    const int h0 = by * TH;

    const int tid  = threadIdx.x;
    const int hw   = tid >> 5;             // 0..9
    const bool comp = hw < ND;             // tid >= 288: stage-only
    const int dyi  = comp ? hw : 0;
    const int l32  = tid & 31;
    const int hs   = l32 >> 2;             // 0..7
    const int wg   = l32 & 3;              // 0..3; outputs w = w0 + wg*8 + 0..7

    // ---- staging: every thread owns one (cp, row, quad) slot of f2 ----
    const int scp = tid / 160;             // channel-pair 0/1
    const int st  = tid % 160;
    const int sr  = st / QPR;              // 0..15
    const int sq  = st % QPR;              // 0..9
    const int gh  = h0 - 4 + sr;
    const int gw  = w0 - 4 + sq * 4;
    const bool rok = (gh >= 0) && (gh < H_);
    const bool mk0 = rok && (gw + 0 >= 0) && (gw + 0 < W_);
    const bool mk1 = rok && (gw + 1 >= 0) && (gw + 1 < W_);
    const bool mk2 = rok && (gw + 2 >= 0) && (gw + 2 < W_);
    const bool mk3 = rok && (gw + 3 >= 0) && (gw + 3 < W_);
    const int ghc = gh < 0 ? 0 : (gh >= H_ ? H_ - 1 : gh);
    const int gwc = gw < 0 ? 0 : (gw > W_ - 4 ? W_ - 4 : gw);
    const size_t gBase = (size_t)b * C_ * HW + (size_t)ghc * W_ + gwc;

    float4 lo, hi;                          // in-flight f2 loads (ch c, c+1)
    float4 nsq = make_float4(0.f, 0.f, 0.f, 0.f);

    auto issueLoads = [&](int c0) {
        const float* p = f2g + gBase + (size_t)(c0 + 2 * scp) * HW;
        lo = *reinterpret_cast<const float4*>(p);
        hi = *reinterpret_cast<const float4*>(p + HW);
    };

    auto writeStage = [&](int buf) {
        const float x0 = mk0 ? lo.x : 0.f, y0 = mk0 ? hi.x : 0.f;
        const float x1 = mk1 ? lo.y : 0.f, y1 = mk1 ? hi.y : 0.f;
        const float x2 = mk2 ? lo.z : 0.f, y2 = mk2 ? hi.z : 0.f;
        const float x3 = mk3 ? lo.w : 0.f, y3 = mk3 ? hi.w : 0.f;
        const unsigned u0 = pk2(x0, y0), u1 = pk2(x1, y1);
        const unsigned u2 = pk2(x2, y2), u3 = pk2(x3, y3);
        nsq.x = dot2f(u0, u0, nsq.x);      // norms from quantized values: bias cancels
        nsq.y = dot2f(u1, u1, nsq.y);
        nsq.z = dot2f(u2, u2, nsq.z);
        nsq.w = dot2f(u3, u3, nsq.w);
        *reinterpret_cast<uint4*>(&sf2[buf][scp][sr][sq * 4]) = make_uint4(u0, u1, u2, u3);
    };

    float acc[WPT][ND];
#pragma unroll
    for (int i = 0; i < WPT; ++i)
#pragma unroll
        for (int j = 0; j < ND; ++j) acc[i][j] = 0.f;
    float n1[WPT];
#pragma unroll
    for (int i = 0; i < WPT; ++i) n1[i] = 0.f;

    // f1 read direct from global (L1-hot: same addresses across all dy waves)
    const float* f1base = f1g + (size_t)b * C_ * HW + (size_t)(h0 + hs) * W_ + (w0 + wg * 8);
    const int rrow = hs + dyi;             // 0..15

    auto computeChunk = [&](int buf, int c0) {
        if (!comp) return;
#pragma unroll
        for (int cp = 0; cp < 2; ++cp) {
            const float* pa = f1base + (size_t)(c0 + 2 * cp) * HW;
            const float4 a0 = *reinterpret_cast<const float4*>(pa);
            const float4 a1 = *reinterpret_cast<const float4*>(pa + 4);
            const float4 b0 = *reinterpret_cast<const float4*>(pa + HW);
            const float4 b1 = *reinterpret_cast<const float4*>(pa + HW + 4);
            unsigned a[8];
            a[0] = pk2(a0.x, b0.x); a[1] = pk2(a0.y, b0.y);
            a[2] = pk2(a0.z, b0.z); a[3] = pk2(a0.w, b0.w);
            a[4] = pk2(a1.x, b1.x); a[5] = pk2(a1.y, b1.y);
            a[6] = pk2(a1.z, b1.z); a[7] = pk2(a1.w, b1.w);
#pragma unroll
            for (int i = 0; i < 8; ++i) n1[i] = dot2f(a[i], a[i], n1[i]);
            const unsigned* wp = &sf2[buf][cp][rrow][wg * 8];
            const uint4 q0 = *reinterpret_cast<const uint4*>(wp);
            const uint4 q1 = *reinterpret_cast<const uint4*>(wp + 4);
            const uint4 q2 = *reinterpret_cast<const uint4*>(wp + 8);
            const uint4 q3 = *reinterpret_cast<const uint4*>(wp + 12);
            const unsigned v[16] = {q0.x, q0.y, q0.z, q0.w, q1.x, q1.y, q1.z, q1.w,
                                    q2.x, q2.y, q2.z, q2.w, q3.x, q3.y, q3.z, q3.w};
#pragma unroll
            for (int wi = 0; wi < 8; ++wi)
#pragma unroll
                for (int d = 0; d < ND; ++d)
                    acc[wi][d] = dot2f(a[wi], v[wi + d], acc[wi][d]);
        }
    };

    // ---- main loop: issue(t+1) -> compute(t) -> pack+write(t+1) -> barrier ----
    issueLoads(0); writeStage(0);
    __syncthreads();
    for (int t = 0; t < NCHUNK; ++t) {
        const bool more = (t + 1) < NCHUNK;
        if (more) issueLoads((t + 1) * KC);
        computeChunk(t & 1, t * KC);
        if (more) writeStage((t + 1) & 1);
        __syncthreads();
    }

    // ---- f2 norms: cp-partial sums into dead buffer-0 regions ----
    float* nA = reinterpret_cast<float*>(&sf2[0][0][0][0]);   // [16][44] cp0 partial
    float* nB = reinterpret_cast<float*>(&sf2[0][1][0][0]);   // [16][44] cp1 partial
    {
        float* np = (scp ? nB : nA) + sr * F2S + sq * 4;
        *reinterpret_cast<float4*>(np) = nsq;
    }
    __syncthreads();

    if (comp) {
        float inv1[WPT];
#pragma unroll
        for (int i = 0; i < WPT; ++i)
            inv1[i] = 1.0f / fmaxf(sqrtf(n1[i]), 1e-12f);
        float inv2[16];
#pragma unroll
        for (int kk = 0; kk < 16; ++kk) {
            const int idx = rrow * F2S + wg * 8 + kk;
            inv2[kk] = 1.0f / fmaxf(sqrtf(nA[idx] + nB[idx]), 1e-12f);
        }
        const int h = h0 + hs;
#pragma unroll
        for (int d = 0; d < ND; ++d) {
            float o[WPT];
#pragma unroll
            for (int wi = 0; wi < WPT; ++wi)
                o[wi] = acc[wi][d] * inv1[wi] * inv2[wi + d];
            float* op = outg + ((size_t)(b * 81 + dyi * ND + d) * H_ + h) * W_ + w0 + wg * 8;
            *reinterpret_cast<float4*>(&op[0]) = make_float4(o[0], o[1], o[2], o[3]);
            *reinterpret_cast<float4*>(&op[4]) = make_float4(o[4], o[5], o[6], o[7]);
        }
    }
}

} // namespace

extern "C" void kernel_launch(void* const* d_in, const int* in_sizes, int n_in,
                              void* d_out, int out_size, void* d_ws, size_t ws_size,
                              hipStream_t stream)
{
    (void)in_sizes; (void)n_in; (void)d_ws; (void)ws_size; (void)out_size;
    const float* f1 = (const float*)d_in[0];
    const float* f2 = (const float*)d_in[1];
    float* out = (float*)d_out;

    dim3 grid(768, 1, 1);      // 6x16x8 tiles, XCD-chunked inside kernel
    dim3 block(NTHREADS);      // 320 threads = 5 waves
    local_corr_kernel<<<grid, block, 0, stream>>>(f1, f2, out);
}

// Round 7
// 189.303 us; speedup vs baseline: 1.6376x; 1.6376x over previous
//
#include <hip/hip_runtime.h>
#include <math.h>

namespace {

constexpr int B_ = 8, C_ = 256, H_ = 128, W_ = 192;
constexpr int HW = H_ * W_;
constexpr int TH = 4;                 // h rows per block
constexpr int TW = 32;                // w cols per block (2 m-tiles)
constexpr int NTHREADS = 576;         // 9 waves, wave = dy
constexpr int KCH = 32;               // channels per k-chunk (one MFMA K)
constexpr int NCHUNK = C_ / KCH;      // 8
constexpr int BROWS = 12;             // staged f2 rows  (h0-4 .. h0+7)
constexpr int BPOS = 48;              // staged f2 cols  (w0-4 .. w0+43), 3 tiles
constexpr int POSB = 80;              // bytes per pos: 32ch*2B + 16 pad (odd slots)
constexpr int TILEB = 16 * POSB;      // 1280 B per 16-pos fragment tile
constexpr int ATILES = TH * 2;        // 8
constexpr int BTILES = BROWS * 3;     // 36
constexpr int BUFB = (ATILES + BTILES) * TILEB;   // 56320 B per buffer
// epilogue overlay (buffer-0 region, dead after last compute reads buffer 1):
constexpr int OSTR = 144;             // out-LDS row stride bytes (36 f32)
constexpr int NP1OFF = 46720;         // 512 f32 f1-norm partials
constexpr int INV1OFF = 48768;        // 128 f32
constexpr int INV2OFF = 49280;        // 576 f32

typedef _Float16 f16x8 __attribute__((ext_vector_type(8)));
typedef float f32x4 __attribute__((ext_vector_type(4)));
typedef _Float16 h2 __attribute__((ext_vector_type(2)));

__device__ __forceinline__ unsigned pk2(float x, float y) {
    return __builtin_bit_cast(unsigned, __builtin_amdgcn_cvt_pkrtz(x, y));
}
__device__ __forceinline__ float dot2f(unsigned a, unsigned b, float c) {
#if __has_builtin(__builtin_amdgcn_fdot2)
    return __builtin_amdgcn_fdot2(__builtin_bit_cast(h2, a),
                                  __builtin_bit_cast(h2, b), c, false);
#else
    const h2 ha = __builtin_bit_cast(h2, a), hb = __builtin_bit_cast(h2, b);
    return fmaf((float)ha.x, (float)hb.x, fmaf((float)ha.y, (float)hb.y, c));
#endif
}

__global__ __launch_bounds__(NTHREADS, 2)
void local_corr_mfma(const float* __restrict__ f1g,
                     const float* __restrict__ f2g,
                     float* __restrict__ outg)
{
    __shared__ __align__(16) char lds[2 * BUFB];   // 112640 B

    // XCD swizzle: batch image == XCD id; within XCD w-major for f2 row reuse
    const int m  = blockIdx.x;            // 0..1535
    const int b  = m & 7;
    const int k  = m >> 3;                // 0..191
    const int bx = k % 6;
    const int by = k / 6;                 // 0..31
    const int w0 = bx * TW, h0 = by * TH;

    const int tid  = threadIdx.x;
    const int dyi  = tid >> 6;            // wave = dy 0..8
    const int lane = tid & 63;
    const int lp   = lane & 15;           // fragment pos index (m or n)
    const int lg   = lane >> 4;           // k-group

    // ---- B staging: thread owns f2 pos tid (all 4 ch-octets) ----
    const int brow = tid / BPOS, bpc = tid % BPOS;   // 12 x 48 = 576
    const int bgh = h0 - 4 + brow, bgw = w0 - 4 + bpc;
    const bool bok = (bgh >= 0) && (bgh < H_) && (bgw >= 0) && (bgw < W_);
    const int bghc = bgh < 0 ? 0 : (bgh >= H_ ? H_ - 1 : bgh);
    const int bgwc = bgw < 0 ? 0 : (bgw >= W_ ? W_ - 1 : bgw);
    const size_t bbase = (size_t)b * C_ * HW + (size_t)bghc * W_ + bgwc;
    const int bwoff = (ATILES + brow * 3 + bpc / 16) * TILEB + (bpc % 16) * POSB;

    // ---- A staging: threads < 512, one ch-octet of f1 pos (t&127) ----
    const bool hasA = tid < 512;
    const int aoct = tid >> 7, apos = tid & 127;
    const int ah = apos >> 5, aw = apos & 31;
    const size_t abase = (size_t)b * C_ * HW + (size_t)(h0 + ah) * W_ + (w0 + aw);
    const int awoff = (ah * 2 + aw / 16) * TILEB + (aw % 16) * POSB + aoct * 16;

    float bv[4][8], av[8];
    float bn = 0.f, an = 0.f;             // f16-value squared norms

    auto issueLoads = [&](int c0) {
#pragma unroll
        for (int o = 0; o < 4; ++o)
#pragma unroll
            for (int j = 0; j < 8; ++j)
                bv[o][j] = f2g[bbase + (size_t)(c0 + 8 * o + j) * HW];
        if (hasA)
#pragma unroll
            for (int j = 0; j < 8; ++j)
                av[j] = f1g[abase + (size_t)(c0 + 8 * aoct + j) * HW];
    };

    auto writeStage = [&](int buf) {
        char* base = lds + buf * BUFB;
#pragma unroll
        for (int o = 0; o < 4; ++o) {
            unsigned u[4];
#pragma unroll
            for (int q = 0; q < 4; ++q) {
                const float x = bok ? bv[o][2 * q] : 0.f;
                const float y = bok ? bv[o][2 * q + 1] : 0.f;
                u[q] = pk2(x, y);
                bn = dot2f(u[q], u[q], bn);
            }
            *reinterpret_cast<uint4*>(base + bwoff + o * 16) =
                make_uint4(u[0], u[1], u[2], u[3]);
        }
        if (hasA) {
            unsigned u[4];
#pragma unroll
            for (int q = 0; q < 4; ++q) {
                u[q] = pk2(av[2 * q], av[2 * q + 1]);
                an = dot2f(u[q], u[q], an);
            }
            *reinterpret_cast<uint4*>(base + awoff) = make_uint4(u[0], u[1], u[2], u[3]);
        }
    };

    f32x4 acc[TH][4];                     // [h][mt0bt0, mt0bt1, mt1bt1, mt1bt2]
#pragma unroll
    for (int h = 0; h < TH; ++h)
#pragma unroll
        for (int j = 0; j < 4; ++j) acc[h][j] = (f32x4)0.f;

    const int fro = lp * POSB + lg * 16;  // fragment read offset within tile

    auto computeChunk = [&](int buf) {
        const char* base = lds + buf * BUFB;
#pragma unroll
        for (int h = 0; h < TH; ++h) {
            const char* at = base + (h * 2) * TILEB;
            const f16x8 fa0 = *reinterpret_cast<const f16x8*>(at + fro);
            const f16x8 fa1 = *reinterpret_cast<const f16x8*>(at + TILEB + fro);
            const char* bt = base + (ATILES + (h + dyi) * 3) * TILEB;
            const f16x8 fb0 = *reinterpret_cast<const f16x8*>(bt + fro);
            const f16x8 fb1 = *reinterpret_cast<const f16x8*>(bt + TILEB + fro);
            const f16x8 fb2 = *reinterpret_cast<const f16x8*>(bt + 2 * TILEB + fro);
            acc[h][0] = __builtin_amdgcn_mfma_f32_16x16x32_f16(fa0, fb0, acc[h][0], 0, 0, 0);
            acc[h][1] = __builtin_amdgcn_mfma_f32_16x16x32_f16(fa0, fb1, acc[h][1], 0, 0, 0);
            acc[h][2] = __builtin_amdgcn_mfma_f32_16x16x32_f16(fa1, fb1, acc[h][2], 0, 0, 0);
            acc[h][3] = __builtin_amdgcn_mfma_f32_16x16x32_f16(fa1, fb2, acc[h][3], 0, 0, 0);
        }
    };

    // ---- pipelined K loop: issue(t+1) | compute(t) | pack+write(t+1) | barrier ----
    issueLoads(0);
    writeStage(0);
    __syncthreads();
    for (int t = 0; t < NCHUNK; ++t) {
        if (t + 1 < NCHUNK) issueLoads((t + 1) * KCH);
        computeChunk(t & 1);
        if (t + 1 < NCHUNK) writeStage((t + 1) & 1);
        __syncthreads();
    }
    // last compute read buffer 1; buffer 0 region is now dead -> overlay epilogue

    // ---- norms -> inv arrays ----
    float* nf1p = reinterpret_cast<float*>(lds + NP1OFF);
    float* inv2 = reinterpret_cast<float*>(lds + INV2OFF);
    if (hasA) nf1p[aoct * 128 + apos] = an;
    inv2[tid] = 1.0f / fmaxf(sqrtf(bn), 1e-12f);
    __syncthreads();
    float* inv1 = reinterpret_cast<float*>(lds + INV1OFF);
    if (tid < 128) {
        const float s = nf1p[tid] + nf1p[128 + tid] + nf1p[256 + tid] + nf1p[384 + tid];
        inv1[tid] = 1.0f / fmaxf(sqrtf(s), 1e-12f);    // index = ah*32 + aw
    }
    __syncthreads();

    // ---- normalize + band-masked transpose into out-LDS [81][TH][32] ----
#pragma unroll
    for (int h = 0; h < TH; ++h) {
#pragma unroll
        for (int j = 0; j < 4; ++j) {
            const int mt = j >> 1, bt = mt + (j & 1);
            const float v2 = inv2[(h + dyi) * BPOS + bt * 16 + lp];   // n = lp
#pragma unroll
            for (int r = 0; r < 4; ++r) {
                const int mloc = 4 * lg + r;
                const int band = lp - mloc + ((j & 1) ? 16 : 0);      // dx+4
                if (band >= 0 && band <= 8) {
                    // FIX R6: inv1 is indexed by f1 position h*32+w, not just w
                    const float v1 = inv1[h * 32 + mt * 16 + mloc];
                    const int od = dyi * 9 + band;
                    float* orow = reinterpret_cast<float*>(lds + (od * TH + h) * OSTR);
                    orow[mt * 16 + mloc] = acc[h][j][r] * v1 * v2;
                }
            }
        }
    }
    __syncthreads();

    // ---- coalesced store: 81*4*8 = 2592 float4 quads ----
    const size_t obase = (size_t)b * 81 * HW;
    for (int s = tid; s < 81 * TH * 8; s += NTHREADS) {
        const int od = s >> 5;            // 32 quads per od
        const int rem = s & 31;
        const int h = rem >> 3, q = rem & 7;
        const float4 v = *reinterpret_cast<const float4*>(lds + (od * TH + h) * OSTR + q * 16);
        *reinterpret_cast<float4*>(outg + obase + (size_t)od * HW +
                                   (size_t)(h0 + h) * W_ + w0 + q * 4) = v;
    }
}

} // namespace

extern "C" void kernel_launch(void* const* d_in, const int* in_sizes, int n_in,
                              void* d_out, int out_size, void* d_ws, size_t ws_size,
                              hipStream_t stream)
{
    (void)in_sizes; (void)n_in; (void)d_ws; (void)ws_size; (void)out_size;
    const float* f1 = (const float*)d_in[0];
    const float* f2 = (const float*)d_in[1];
    float* out = (float*)d_out;

    dim3 grid(1536, 1, 1);     // 8b x 32hb x 6wb, XCD-chunked inside kernel
    dim3 block(NTHREADS);      // 576 threads = 9 waves (wave = dy)
    local_corr_mfma<<<grid, block, 0, stream>>>(f1, f2, out);
}